// Round 5
// baseline (2229.036 us; speedup 1.0000x reference)
//
#include <hip/hip_runtime.h>
#include <math.h>

// Problem constants (from reference)
#define VSZ   50000
#define EDIM  256
#define HDIM  256
#define H2D   128
#define NCLS  12
#define NB    64
#define NL    512
#define G4    512      // 4*H2
#define NNC   1024     // gates for both directions
#define MM    32768    // NL*NB rows
#define START_TAG 10
#define STOP_TAG  11
#define IMPOSSIBLE -10000.0f

__device__ __forceinline__ float sigmoidf_(float x) {
    return 1.0f / (1.0f + expf(-x));
}

// ---------------------------------------------------------------------------
// K1/K3: gates_x = A @ [W_ih_f;W_ih_r]^T + (b_ih+b_hh)
// (unchanged from R3/R4 — not the bottleneck this round; clean attribution)
// ---------------------------------------------------------------------------
template <bool GATHER>
__global__ __launch_bounds__(256)
void gemm_gates(const float* __restrict__ A,
                const int*   __restrict__ gidx,
                const float* __restrict__ wf,   // [512][256]
                const float* __restrict__ wr,   // [512][256]
                const float* __restrict__ bihf, const float* __restrict__ bhhf,
                const float* __restrict__ bihr, const float* __restrict__ bhhr,
                float* __restrict__ out)
{
    __shared__ __align__(16) float As[32][132];   // transposed A tile [k][m]
    __shared__ __align__(16) float Bs[32][132];   // transposed B tile [k][n]

    const int tid = threadIdx.x;
    const int n0  = blockIdx.x * 128;
    const int m0  = blockIdx.y * 128;

    const int w    = tid >> 6;
    const int lane = tid & 63;
    const int wm   = w >> 1;
    const int wn   = w & 1;
    const int am   = lane >> 3;
    const int bn   = lane & 7;
    const int ma   = wm * 64 + am * 8;
    const int nb   = wn * 64 + bn * 8;

    float acc[8][8];
#pragma unroll
    for (int i = 0; i < 8; ++i)
#pragma unroll
        for (int jj = 0; jj < 8; ++jj) acc[i][jj] = 0.0f;

    const bool   fwdside = (n0 < 512);
    const float* wsrc    = fwdside ? wf : wr;
    const int    nbase   = fwdside ? n0 : (n0 - 512);

    int srcA[4];
#pragma unroll
    for (int it = 0; it < 4; ++it) {
        int li  = tid + it * 256;
        int row = m0 + (li >> 3);
        srcA[it] = GATHER ? gidx[row] : row;
    }

    for (int kt = 0; kt < 8; ++kt) {
#pragma unroll
        for (int it = 0; it < 4; ++it) {
            int li = tid + it * 256;
            int r  = li >> 3;
            int c4 = li & 7;
            float4 v = ((const float4*)A)[(size_t)srcA[it] * 64 + kt * 8 + c4];
            As[c4 * 4 + 0][r] = v.x;
            As[c4 * 4 + 1][r] = v.y;
            As[c4 * 4 + 2][r] = v.z;
            As[c4 * 4 + 3][r] = v.w;
        }
#pragma unroll
        for (int it = 0; it < 4; ++it) {
            int li = tid + it * 256;
            int r  = li >> 3;
            int c4 = li & 7;
            float4 v = ((const float4*)wsrc)[(size_t)(nbase + r) * 64 + kt * 8 + c4];
            Bs[c4 * 4 + 0][r] = v.x;
            Bs[c4 * 4 + 1][r] = v.y;
            Bs[c4 * 4 + 2][r] = v.z;
            Bs[c4 * 4 + 3][r] = v.w;
        }
        __syncthreads();

#pragma unroll
        for (int k = 0; k < 32; ++k) {
            float a[8], b[8];
            *(float4*)&a[0] = *(const float4*)&As[k][ma];
            *(float4*)&a[4] = *(const float4*)&As[k][ma + 4];
            *(float4*)&b[0] = *(const float4*)&Bs[k][nb];
            *(float4*)&b[4] = *(const float4*)&Bs[k][nb + 4];
#pragma unroll
            for (int i = 0; i < 8; ++i)
#pragma unroll
                for (int jj = 0; jj < 8; ++jj)
                    acc[i][jj] = fmaf(a[i], b[jj], acc[i][jj]);
        }
        __syncthreads();
    }

    float bias[8];
#pragma unroll
    for (int jj = 0; jj < 8; ++jj) {
        int gn = n0 + nb + jj;
        bias[jj] = fwdside ? (bihf[gn] + bhhf[gn]) : (bihr[gn - 512] + bhhr[gn - 512]);
    }
#pragma unroll
    for (int i = 0; i < 8; ++i) {
        int m = m0 + ma + i;
        float4 s0, s1;
        s0.x = acc[i][0] + bias[0]; s0.y = acc[i][1] + bias[1];
        s0.z = acc[i][2] + bias[2]; s0.w = acc[i][3] + bias[3];
        s1.x = acc[i][4] + bias[4]; s1.y = acc[i][5] + bias[5];
        s1.z = acc[i][6] + bias[6]; s1.w = acc[i][7] + bias[7];
        float4* op = (float4*)(out + (size_t)m * NNC + n0 + nb);
        op[0] = s0;
        op[1] = s1;
    }
}

// ---------------------------------------------------------------------------
// K2/K4: LSTM recurrence v5. 128 blocks = 64 batch x 2 dir; 1024 threads.
//   row = tid & 511 (gate row), kh = tid >> 9 (K-half, wave-uniform).
// Each thread holds 64 weights W[row][kh*64..+63] in VGPRs. 1024-thread
// block structurally caps VGPR at 128; pressure ~95 -> natural residency
// (R1: VGPR=80 => weights re-streamed from L2 = 16.8TB/34.5TB/s = 487us;
//  R4: asm "pin" forced w[] into scratch, VGPR=84, 567us LDS-wall).
// h broadcast: ONE ds_read_b32 per lane (hv = h[kh*64+lane]) then
// v_readlane -> SGPR feeds the FMA directly: ~2 LDS instr/thread/step
// instead of 32 (R4's 256 LDS instr/CU/step x ~10cyc = the 2657cyc wall).
// Half-dots combine via partial[1024] in LDS; threads<128 do all 4 gate
// activations + c/h update. 2 barriers/step.
// ---------------------------------------------------------------------------
__global__ __launch_bounds__(1024, 4)
void lstm_rec(const float* __restrict__ gx,    // [MM][1024]
              const float* __restrict__ whf,   // [512][128]
              const float* __restrict__ whr,
              const float* __restrict__ h0,    // [2][64][128]
              const float* __restrict__ c0,
              float* __restrict__ out)         // [MM][256]
{
    __shared__ __align__(16) float h_lds[H2D];
    __shared__ __align__(16) float partial[1024];

    const int tid = threadIdx.x;               // 0..1023
    const int row = tid & 511;                 // gate row
    const int kh  = tid >> 9;                  // K-half (wave-uniform)
    const int dir = blockIdx.x >> 6;
    const int bb  = blockIdx.x & 63;
    const float* W = dir ? whr : whf;

    // 64 weights -> VGPRs (scalar, constant-indexed => registers)
    float wreg[64];
    {
        const float4* wp = (const float4*)(W + (size_t)row * H2D + kh * 64);
#pragma unroll
        for (int k = 0; k < 16; ++k) {
            float4 v = wp[k];
            wreg[4 * k + 0] = v.x; wreg[4 * k + 1] = v.y;
            wreg[4 * k + 2] = v.z; wreg[4 * k + 3] = v.w;
        }
    }

    float creg = 0.0f;
    if (tid < H2D) {
        h_lds[tid] = h0[dir * (NB * H2D) + bb * H2D + tid];
        creg       = c0[dir * (NB * H2D) + bb * H2D + tid];
    }
    __syncthreads();

    const int  lane = tid & 63;
    const bool upd  = (tid < H2D);             // update threads (waves 0-1)

    // gx for the 4 gates of element `tid` (updaters only), 1-step prefetch
    const size_t gxbase = (size_t)dir * 512 + tid;   // + 128*k
    float gxc[4] = {0.f, 0.f, 0.f, 0.f};
    if (upd) {
        const int tf = dir ? (NL - 1) : 0;
        const size_t mo = ((size_t)tf * NB + bb) * NNC + gxbase;
#pragma unroll
        for (int k = 0; k < 4; ++k) gxc[k] = gx[mo + 128 * k];
    }

    for (int ti = 0; ti < NL; ++ti) {
        const int t = dir ? (NL - 1 - ti) : ti;
        const size_t m = (size_t)t * NB + bb;

        // ---- all threads: half-dot for (row, kh) ----
        const float hv  = h_lds[kh * 64 + lane];   // 1 ds_read_b32, 2-way (free)
        const int   hvi = __float_as_int(hv);

        // prefetch next step's gx (independent of h; hides HBM latency)
        float gxn[4];
        if (upd && ti + 1 < NL) {
            const int tn = dir ? (NL - 2 - ti) : (ti + 1);
            const size_t mo = ((size_t)tn * NB + bb) * NNC + gxbase;
#pragma unroll
            for (int k = 0; k < 4; ++k) gxn[k] = gx[mo + 128 * k];
        }

        float a0 = 0.f, a1 = 0.f, a2 = 0.f, a3 = 0.f;
#pragma unroll
        for (int i = 0; i < 64; i += 4) {
            const float s0 = __int_as_float(__builtin_amdgcn_readlane(hvi, i + 0));
            const float s1 = __int_as_float(__builtin_amdgcn_readlane(hvi, i + 1));
            const float s2 = __int_as_float(__builtin_amdgcn_readlane(hvi, i + 2));
            const float s3 = __int_as_float(__builtin_amdgcn_readlane(hvi, i + 3));
            a0 = fmaf(wreg[i + 0], s0, a0);
            a1 = fmaf(wreg[i + 1], s1, a1);
            a2 = fmaf(wreg[i + 2], s2, a2);
            a3 = fmaf(wreg[i + 3], s3, a3);
        }
        const float half = (a0 + a1) + (a2 + a3);
        partial[tid] = half;
        __syncthreads();

        // ---- updaters: combine halves, activate all 4 gates, update ----
        if (upd) {
            const float pi = (half + partial[tid + 512]) + gxc[0];
            const float pf = (partial[tid + 128] + partial[tid + 640]) + gxc[1];
            const float pg = (partial[tid + 256] + partial[tid + 768]) + gxc[2];
            const float po = (partial[tid + 384] + partial[tid + 896]) + gxc[3];
            const float ig = sigmoidf_(pi);
            const float fg = sigmoidf_(pf);
            const float gg = tanhf(pg);
            const float og = sigmoidf_(po);
            creg = fg * creg + ig * gg;
            const float hnew = og * tanhf(creg);
            h_lds[tid] = hnew;
            out[m * HDIM + dir * H2D + tid] = hnew;
#pragma unroll
            for (int k = 0; k < 4; ++k) gxc[k] = gxn[k];
        }
        __syncthreads();
    }
}

// ---------------------------------------------------------------------------
// K5: feats = out2 @ w_out^T + b_out   (M=32768, N=12, K=256)
// ---------------------------------------------------------------------------
__global__ __launch_bounds__(256)
void feats_kernel(const float* __restrict__ out2,
                  const float* __restrict__ w_out,   // [12][256]
                  const float* __restrict__ b_out,
                  float* __restrict__ feats)         // [MM][12]
{
    __shared__ __align__(16) float wl[NCLS * HDIM];
    const int tid = threadIdx.x;
#pragma unroll
    for (int i = 0; i < NCLS; ++i) wl[tid + i * 256] = w_out[tid + i * 256];
    __syncthreads();

    const int m = blockIdx.x * 256 + tid;
    float acc[NCLS];
#pragma unroll
    for (int c = 0; c < NCLS; ++c) acc[c] = 0.0f;

    const float4* x4 = (const float4*)out2 + (size_t)m * 64;
    const float4* w4 = (const float4*)wl;
    for (int k4 = 0; k4 < 64; ++k4) {
        float4 x = x4[k4];
#pragma unroll
        for (int c = 0; c < NCLS; ++c) {
            float4 wv = w4[c * 64 + k4];              // LDS broadcast
            acc[c] = fmaf(x.x, wv.x, acc[c]);
            acc[c] = fmaf(x.y, wv.y, acc[c]);
            acc[c] = fmaf(x.z, wv.z, acc[c]);
            acc[c] = fmaf(x.w, wv.w, acc[c]);
        }
    }
#pragma unroll
    for (int c = 0; c < NCLS; ++c)
        feats[(size_t)m * NCLS + c] = acc[c] + b_out[c];
}

// ---------------------------------------------------------------------------
// K6: Viterbi forward + backtrace, fused (LDS backpointers). Unchanged.
// ---------------------------------------------------------------------------
__global__ __launch_bounds__(64)
void viterbi_crf(const float* __restrict__ feats,
                 const float* __restrict__ masks,   // [B][L]
                 const float* __restrict__ trans,   // [12][12]
                 float* __restrict__ out)           // [0:64) score, [64:) path
{
    __shared__ unsigned char bpl[NL][NCLS];
    __shared__ float pathl[NL];

    const int b    = blockIdx.x;
    const int lane = threadIdx.x;

    float tr[NCLS];
#pragma unroll
    for (int jj = 0; jj < NCLS; ++jj)
        tr[jj] = (lane < NCLS) ? trans[lane * NCLS + jj] : 0.0f;

    float msv = (lane == START_TAG) ? 0.0f : IMPOSSIBLE;
    float len = 0.0f;

    float emit_n = (lane < NCLS) ? feats[((size_t)b * NL) * NCLS + lane] : 0.0f;
    float mt_n   = masks[b * NL];

    for (int t = 0; t < NL; ++t) {
        const float emit = emit_n;
        const float mt   = mt_n;
        if (t + 1 < NL) {
            emit_n = (lane < NCLS) ? feats[((size_t)b * NL + t + 1) * NCLS + lane] : 0.0f;
            mt_n   = masks[b * NL + t + 1];
        }
        len += mt;

        float best = -3.4e38f;
        int   bj   = 0;
#pragma unroll
        for (int jj = 0; jj < NCLS; ++jj) {
            float msj = __shfl(msv, jj);
            float v   = msj + tr[jj];
            if (v > best) { best = v; bj = jj; }   // strict > keeps first max
        }
        const float sc = best + emit;
        msv = mt * sc + (1.0f - mt) * msv;
        if (lane < NCLS)
            bpl[t][lane] = (unsigned char)bj;
    }

    const float fin = (lane < NCLS) ? (msv + trans[STOP_TAG * NCLS + lane]) : -3.4e38f;
    float bv = -3.4e38f;
    int   bt = 0;
#pragma unroll
    for (int jj = 0; jj < NCLS; ++jj) {
        float v = __shfl(fin, jj);
        if (v > bv) { bv = v; bt = jj; }
    }
    if (lane == 0) out[b] = bv;

    const int ilen = (int)(len + 0.5f);        // lane-uniform

    __syncthreads();

    int cur = bt;
    for (int t = NL - 1; t >= 0; --t) {
        const int tb  = (t == NL - 1) ? (NL - 1) : (t + 1);
        const int nxt = bpl[tb][cur];
        const int val = (t >= ilen - 1) ? bt : nxt;
        cur = val;
        if (lane == 0) pathl[t] = (t < ilen) ? (float)val : 0.0f;
    }
    __syncthreads();

    float* po = out + 64 + (size_t)b * NL;
#pragma unroll
    for (int i = 0; i < NL / 64; ++i)
        po[lane + i * 64] = pathl[lane + i * 64];
}

// ---------------------------------------------------------------------------
extern "C" void kernel_launch(void* const* d_in, const int* in_sizes, int n_in,
                              void* d_out, int out_size, void* d_ws, size_t ws_size,
                              hipStream_t stream)
{
    const int*   sentence = (const int*)  d_in[0];
    const float* masks    = (const float*)d_in[1];
    const float* emb      = (const float*)d_in[2];
    const float* w_ih_f1  = (const float*)d_in[3];
    const float* w_hh_f1  = (const float*)d_in[4];
    const float* b_ih_f1  = (const float*)d_in[5];
    const float* b_hh_f1  = (const float*)d_in[6];
    const float* w_ih_r1  = (const float*)d_in[7];
    const float* w_hh_r1  = (const float*)d_in[8];
    const float* b_ih_r1  = (const float*)d_in[9];
    const float* b_hh_r1  = (const float*)d_in[10];
    const float* w_ih_f2  = (const float*)d_in[11];
    const float* w_hh_f2  = (const float*)d_in[12];
    const float* b_ih_f2  = (const float*)d_in[13];
    const float* b_hh_f2  = (const float*)d_in[14];
    const float* w_ih_r2  = (const float*)d_in[15];
    const float* w_hh_r2  = (const float*)d_in[16];
    const float* b_ih_r2  = (const float*)d_in[17];
    const float* b_hh_r2  = (const float*)d_in[18];
    const float* w_out    = (const float*)d_in[19];
    const float* b_out    = (const float*)d_in[20];
    const float* trans    = (const float*)d_in[21];
    const float* h0_1     = (const float*)d_in[22];
    const float* c0_1     = (const float*)d_in[23];
    const float* h0_2     = (const float*)d_in[24];
    const float* c0_2     = (const float*)d_in[25];

    // workspace layout (f32); gx reused between layers
    float* gx    = (float*)d_ws;                       // [32768][1024]  134.2 MB
    float* out1  = gx   + (size_t)MM * NNC;            // [32768][256]    33.6 MB
    float* out2  = out1 + (size_t)MM * HDIM;           // [32768][256]    33.6 MB
    float* feats = out2 + (size_t)MM * HDIM;           // [32768][12]      1.6 MB

    dim3 gemm_grid(NNC / 128, MM / 128);   // (8, 256)

    // Layer 1: input gates (gathered through sentence) -> recurrence
    gemm_gates<true><<<gemm_grid, 256, 0, stream>>>(
        emb, sentence, w_ih_f1, w_ih_r1, b_ih_f1, b_hh_f1, b_ih_r1, b_hh_r1, gx);
    lstm_rec<<<128, 1024, 0, stream>>>(gx, w_hh_f1, w_hh_r1, h0_1, c0_1, out1);

    // Layer 2
    gemm_gates<false><<<gemm_grid, 256, 0, stream>>>(
        out1, nullptr, w_ih_f2, w_ih_r2, b_ih_f2, b_hh_f2, b_ih_r2, b_hh_r2, gx);
    lstm_rec<<<128, 1024, 0, stream>>>(gx, w_hh_f2, w_hh_r2, h0_2, c0_2, out2);

    // Projection + fused CRF
    feats_kernel<<<MM / 256, 256, 0, stream>>>(out2, w_out, b_out, feats);
    viterbi_crf<<<NB, 64, 0, stream>>>(feats, masks, trans, (float*)d_out);
}